// Round 2
// baseline (358.697 us; speedup 1.0000x reference)
//
#include <hip/hip_runtime.h>
#include <math.h>

#define NUM_K   1024
#define CDIM    64
#define HW      1024          // 32*32
#define NROWS   65536         // 64*1024
#define RPB     64            // rows per block
#define NBLK    (NROWS / RPB) // 1024

// numpy pairwise_sum order for n=64 contiguous fp32 (8 stride-8 chains,
// ((r0+r1)+(r2+r3))+((r4+r5)+(r6+r7))), squares rounded separately (no FMA).
__device__ __forceinline__ float np_sumsq64(const float* a) {
#pragma clang fp contract(off)
  float r0 = a[0]*a[0], r1 = a[1]*a[1], r2 = a[2]*a[2], r3 = a[3]*a[3];
  float r4 = a[4]*a[4], r5 = a[5]*a[5], r6 = a[6]*a[6], r7 = a[7]*a[7];
#pragma unroll
  for (int i = 8; i < 64; i += 8) {
    r0 += a[i+0]*a[i+0]; r1 += a[i+1]*a[i+1];
    r2 += a[i+2]*a[i+2]; r3 += a[i+3]*a[i+3];
    r4 += a[i+4]*a[i+4]; r5 += a[i+5]*a[i+5];
    r6 += a[i+6]*a[i+6]; r7 += a[i+7]*a[i+7];
  }
  return ((r0+r1)+(r2+r3))+((r4+r5)+(r6+r7));
}

__global__ void vq_norms(const float* __restrict__ emb, float* __restrict__ norms) {
  int k = blockIdx.x * blockDim.x + threadIdx.x;
  if (k < NUM_K) norms[k] = np_sumsq64(emb + k * CDIM);
}

// e/norms are wave-uniform per k -> scalar loads (SMEM/K$), no LDS staging.
// x[64] stays in VGPRs: waves_per_eu(2,4) raises the allocator budget past the
// 64-VGPR occupancy heuristic that caused spills/remat in round 1.
__global__ __attribute__((amdgpu_flat_work_group_size(256, 256),
                          amdgpu_waves_per_eu(2, 4)))
void vq_main(const float* __restrict__ xin, const float* __restrict__ emb,
             const float* __restrict__ norms, float* __restrict__ out0,
             float* __restrict__ out_idx, double* __restrict__ partials,
             unsigned int* __restrict__ counts)
{
  __shared__ unsigned int hist_s[NUM_K];    // 4 KB
  __shared__ float dmin_s[3 * RPB];
  __shared__ int   kmin_s[3 * RPB];

  const int t  = threadIdx.x;
  // wave id; readfirstlane makes it provably wave-uniform -> k is uniform ->
  // emb/norms loads become s_load through the constant cache.
  const int p  = __builtin_amdgcn_readfirstlane(t >> 6);   // k ≡ p (mod 4)
  const int r  = t & 63;        // row within block
  const int n  = blockIdx.x * RPB + r;
  const int b  = n >> 10;
  const int hw = n & (HW - 1);

  for (int i = t; i < NUM_K; i += 256) hist_s[i] = 0;

  // load this row's x (BHWC gather; coalesced across lanes per c)
  const float* xb = xin + (size_t)b * (CDIM * HW) + hw;
  float x[CDIM];
#pragma unroll
  for (int c = 0; c < CDIM; ++c) x[c] = xb[c * HW];

  const float S = np_sumsq64(x);   // bit-matches np.sum(x*x, axis=1)

  float dmin = INFINITY;
  int   kmin = 0;

  // two k's in flight (k0 = 8g+p, k1 = k0+4): 2 independent FMA chains
  // saturate the VALU pipe; per-k dot order identical to round 1 (c ascending).
#pragma unroll 2
  for (int g = 0; g < 128; ++g) {
    const int k0 = 8 * g + p;
    const int k1 = k0 + 4;
    const float4* e0p = (const float4*)(emb + (size_t)k0 * CDIM);
    const float4* e1p = (const float4*)(emb + (size_t)k1 * CDIM);
    const float n0 = norms[k0];
    const float n1 = norms[k1];
    float d0 = 0.f, d1 = 0.f;
#pragma unroll
    for (int c4 = 0; c4 < 16; ++c4) {
      const float4 a0 = e0p[c4];
      const float4 a1 = e1p[c4];
      const float x0 = x[4*c4+0], x1 = x[4*c4+1], x2 = x[4*c4+2], x3 = x[4*c4+3];
      d0 = fmaf(x0, a0.x, d0); d1 = fmaf(x0, a1.x, d1);
      d0 = fmaf(x1, a0.y, d0); d1 = fmaf(x1, a1.y, d1);
      d0 = fmaf(x2, a0.z, d0); d1 = fmaf(x2, a1.z, d1);
      d0 = fmaf(x3, a0.w, d0); d1 = fmaf(x3, a1.w, d1);
    }
    // d = fl(fl(S - 2*dot) + n_k); 2*dot exact so FMA contraction is bit-identical
    const float q0 = (S - 2.0f * d0) + n0;
    const float q1 = (S - 2.0f * d1) + n1;
    if (q0 < dmin) { dmin = q0; kmin = k0; }
    if (q1 < dmin) { dmin = q1; kmin = k1; }
  }

  // lexicographic (d, k) merge across the 4 k-parities = np first-min semantics
  if (p != 0) {
    dmin_s[(p - 1) * RPB + r] = dmin;
    kmin_s[(p - 1) * RPB + r] = kmin;
  }
  __syncthreads();
  if (p == 0) {
#pragma unroll
    for (int q = 0; q < 3; ++q) {
      const float dq = dmin_s[q * RPB + r];
      const int   kq = kmin_s[q * RPB + r];
      if (dq < dmin || (dq == dmin && kq < kmin)) { dmin = dq; kmin = kq; }
    }
    out_idx[n] = (float)kmin;
    atomicAdd(&hist_s[kmin], 1u);

    // epilogue: quantized_st = fl(x + fl(q - x)); loss partial
    const float4* eb = (const float4*)(emb + (size_t)kmin * CDIM);
    float4* o = (float4*)(out0 + (size_t)n * CDIM);
    float ssq = 0.f;
#pragma unroll
    for (int c4 = 0; c4 < 16; ++c4) {
      const float4 q4 = eb[c4];
      const float x0 = x[4*c4+0], x1 = x[4*c4+1], x2 = x[4*c4+2], x3 = x[4*c4+3];
      const float u0 = q4.x - x0, u1 = q4.y - x1, u2 = q4.z - x2, u3 = q4.w - x3;
      ssq = fmaf(u0, u0, fmaf(u1, u1, fmaf(u2, u2, fmaf(u3, u3, ssq))));
      o[c4] = make_float4(x0 + u0, x1 + u1, x2 + u2, x3 + u3);
    }
#pragma unroll
    for (int off = 32; off > 0; off >>= 1) ssq += __shfl_down(ssq, off, 64);
    if (r == 0) partials[blockIdx.x] = (double)ssq;   // deterministic, no FP atomics
  }
  __syncthreads();
  for (int i = t; i < NUM_K; i += 256) {
    const unsigned int v = hist_s[i];
    if (v) atomicAdd(&counts[i], v);
  }
}

__global__ void vq_final(const double* __restrict__ partials,
                         const unsigned int* __restrict__ counts,
                         float* __restrict__ out_loss, float* __restrict__ out_perp)
{
  __shared__ double sh[256];
  const int t = threadIdx.x;
  double acc = 0.0, ent = 0.0;
  for (int i = t; i < NBLK; i += 256) acc += partials[i];
  for (int k = t; k < NUM_K; k += 256) {
    const double pr = (double)counts[k] * (1.0 / 65536.0);
    ent += pr * log(pr + 1e-10);
  }
  sh[t] = acc;
  __syncthreads();
  for (int s = 128; s > 0; s >>= 1) { if (t < s) sh[t] += sh[t + s]; __syncthreads(); }
  const double total = sh[0];
  __syncthreads();
  sh[t] = ent;
  __syncthreads();
  for (int s = 128; s > 0; s >>= 1) { if (t < s) sh[t] += sh[t + s]; __syncthreads(); }
  if (t == 0) {
    // vq_loss = mean((q-x)^2) * (1 + 0.25); means over N*C = 4194304 elements
    out_loss[0] = (float)(1.25 * total / 4194304.0);
    out_perp[0] = (float)exp(-sh[0]);
  }
}

extern "C" void kernel_launch(void* const* d_in, const int* in_sizes, int n_in,
                              void* d_out, int out_size, void* d_ws, size_t ws_size,
                              hipStream_t stream)
{
  const float* xin = (const float*)d_in[0];
  const float* emb = (const float*)d_in[1];
  float* out = (float*)d_out;

  // ws layout: [0,4K) fp32 norms[1024] | [4K,8K) u32 counts[1024] | [8K,16K) f64 partials[1024]
  float*        norms    = (float*)d_ws;
  unsigned int* counts   = (unsigned int*)((char*)d_ws + 4096);
  double*       partials = (double*)((char*)d_ws + 8192);

  hipMemsetAsync((char*)d_ws + 4096, 0, 4096, stream);  // zero counts only

  vq_norms<<<dim3(4), dim3(256), 0, stream>>>(emb, norms);

  float* out0     = out;                       // 4194304 elements (BHWC flat)
  float* out_loss = out + 4194304;             // scalar
  float* out_idx  = out + 4194305;             // 65536 elements (as float)
  float* out_perp = out + 4194305 + 65536;     // scalar

  vq_main<<<dim3(NBLK), dim3(256), 0, stream>>>(xin, emb, norms, out0, out_idx,
                                                partials, counts);
  vq_final<<<dim3(1), dim3(256), 0, stream>>>(partials, counts, out_loss, out_perp);
}

// Round 3
// 312.113 us; speedup vs baseline: 1.1493x; 1.1493x over previous
//
#include <hip/hip_runtime.h>
#include <math.h>

#define NUM_K   1024
#define CDIM    64
#define HW      1024          // 32*32
#define NROWS   65536         // 64*1024
#define CHUNK   128           // codes per LDS chunk (32 KB)
#define NCHUNK  (NUM_K / CHUNK)
#define RPT     4             // rows per thread (register blocking)
#define RPB     256           // rows per block = 64 lanes * RPT
#define NBLK    (NROWS / RPB) // 256 blocks -> 1 per CU

// numpy pairwise_sum order for n=64 contiguous fp32 (8 stride-8 chains,
// ((r0+r1)+(r2+r3))+((r4+r5)+(r6+r7))), squares rounded separately (no FMA).
__device__ __forceinline__ float np_sumsq64(const float* a) {
#pragma clang fp contract(off)
  float r0 = a[0]*a[0], r1 = a[1]*a[1], r2 = a[2]*a[2], r3 = a[3]*a[3];
  float r4 = a[4]*a[4], r5 = a[5]*a[5], r6 = a[6]*a[6], r7 = a[7]*a[7];
#pragma unroll
  for (int i = 8; i < 64; i += 8) {
    r0 += a[i+0]*a[i+0]; r1 += a[i+1]*a[i+1];
    r2 += a[i+2]*a[i+2]; r3 += a[i+3]*a[i+3];
    r4 += a[i+4]*a[i+4]; r5 += a[i+5]*a[i+5];
    r6 += a[i+6]*a[i+6]; r7 += a[i+7]*a[i+7];
  }
  return ((r0+r1)+(r2+r3))+((r4+r5)+(r6+r7));
}

__global__ void vq_norms(const float* __restrict__ emb, float* __restrict__ norms) {
  int k = blockIdx.x * blockDim.x + threadIdx.x;
  if (k < NUM_K) norms[k] = np_sumsq64(emb + k * CDIM);
}

// async global->LDS, 16 B per lane (wave-uniform base + lane*16 pattern)
typedef const __attribute__((address_space(1))) unsigned int* glds_gp;
typedef __attribute__((address_space(3))) unsigned int* glds_lp;
__device__ __forceinline__ void load_lds16(const void* g, void* l) {
  __builtin_amdgcn_global_load_lds((glds_gp)g, (glds_lp)l, 16, 0, 0);
}

__device__ __forceinline__ void stage_chunk(const float* __restrict__ emb,
                                            const float* __restrict__ norms,
                                            float* e_dst, float* nk_dst,
                                            int cb, int t) {
  const float4* g = (const float4*)(emb + (size_t)cb * CDIM);
  float4* l = (float4*)e_dst;
#pragma unroll
  for (int i = 0; i < (CHUNK * CDIM / 4) / 256; ++i)   // 8 per thread
    load_lds16(g + t + 256 * i, l + t + 256 * i);
  if (t < CHUNK / 4)                                    // 32 float4 of norms
    load_lds16((const float4*)(norms + cb) + t, (float4*)nk_dst + t);
}

// 1 block/CU, 1 wave/SIMD, 512-VGPR budget: x[4][64] lives in registers and
// every broadcast e-read feeds 4 rows (LDS delivery 98k cy/CU < VALU 131k).
__global__ __launch_bounds__(256, 1)
void vq_main(const float* __restrict__ xin, const float* __restrict__ emb,
             const float* __restrict__ norms, float* __restrict__ out0,
             float* __restrict__ out_idx, double* __restrict__ partials,
             unsigned int* __restrict__ counts)
{
  __shared__ float e_s[2 * CHUNK * CDIM];   // 64 KB double-buffered
  __shared__ float nk_s[2 * CHUNK];         // 1 KB
  __shared__ unsigned int hist_s[NUM_K];    // 4 KB
  __shared__ float dmin_s[3 * RPB];         // 3 KB
  __shared__ int   kmin_s[3 * RPB];         // 3 KB

  const int t  = threadIdx.x;
  const int p  = __builtin_amdgcn_readfirstlane(t >> 6);  // k-parity wave
  const int r  = t & 63;
  const int n0 = blockIdx.x * RPB;          // block's first row (mult of 256)
  const int b  = n0 >> 10;                  // same b for all 256 rows
  const int hw0 = (n0 & (HW - 1)) + r;

  for (int i = t; i < NUM_K; i += 256) hist_s[i] = 0;

  // prefetch chunk 0 while we gather x
  stage_chunk(emb, norms, e_s, nk_s, 0, t);

  // 4 rows per lane: n = n0 + 64*j + r (BHWC gather, coalesced across lanes)
  const float* xb = xin + (size_t)b * (CDIM * HW);
  float x[RPT * CDIM];
#pragma unroll
  for (int j = 0; j < RPT; ++j)
#pragma unroll
    for (int c = 0; c < CDIM; ++c)
      x[j * CDIM + c] = xb[(c << 10) + hw0 + 64 * j];

  const float S0 = np_sumsq64(x);
  const float S1 = np_sumsq64(x + 64);
  const float S2 = np_sumsq64(x + 128);
  const float S3 = np_sumsq64(x + 192);

  float dm0 = INFINITY, dm1 = INFINITY, dm2 = INFINITY, dm3 = INFINITY;
  int   km0 = 0, km1 = 0, km2 = 0, km3 = 0;

  __syncthreads();   // chunk 0 staged (barrier drains vmcnt)

  for (int ci = 0; ci < NCHUNK; ++ci) {
    if (ci + 1 < NCHUNK)   // issue next chunk into the other buffer; no wait
      stage_chunk(emb, norms, e_s + ((ci + 1) & 1) * (CHUNK * CDIM),
                  nk_s + ((ci + 1) & 1) * CHUNK, (ci + 1) << 7, t);

    const float* es = e_s + (ci & 1) * (CHUNK * CDIM);
    const float* ns = nk_s + (ci & 1) * CHUNK;
    const int cb = ci << 7;

    for (int m = 0; m < CHUNK / 4; ++m) {       // k ascending within parity
      const int kl = 4 * m + p;
      const float4* ep = (const float4*)(es + kl * CDIM);
      const float nk = ns[kl];
      float d0 = 0.f, d1 = 0.f, d2 = 0.f, d3 = 0.f;
#pragma unroll
      for (int c4 = 0; c4 < 16; ++c4) {
        const float4 a = ep[c4];   // one broadcast b128 serves 4 rows
        d0 = fmaf(x[      4*c4+0], a.x, d0);
        d1 = fmaf(x[ 64 + 4*c4+0], a.x, d1);
        d2 = fmaf(x[128 + 4*c4+0], a.x, d2);
        d3 = fmaf(x[192 + 4*c4+0], a.x, d3);
        d0 = fmaf(x[      4*c4+1], a.y, d0);
        d1 = fmaf(x[ 64 + 4*c4+1], a.y, d1);
        d2 = fmaf(x[128 + 4*c4+1], a.y, d2);
        d3 = fmaf(x[192 + 4*c4+1], a.y, d3);
        d0 = fmaf(x[      4*c4+2], a.z, d0);
        d1 = fmaf(x[ 64 + 4*c4+2], a.z, d1);
        d2 = fmaf(x[128 + 4*c4+2], a.z, d2);
        d3 = fmaf(x[192 + 4*c4+2], a.z, d3);
        d0 = fmaf(x[      4*c4+3], a.w, d0);
        d1 = fmaf(x[ 64 + 4*c4+3], a.w, d1);
        d2 = fmaf(x[128 + 4*c4+3], a.w, d2);
        d3 = fmaf(x[192 + 4*c4+3], a.w, d3);
      }
      // d = fl(fl(S - 2*dot) + n_k); *2 exact so contraction is bit-identical
      const float q0 = (S0 - 2.0f * d0) + nk;
      const float q1 = (S1 - 2.0f * d1) + nk;
      const float q2 = (S2 - 2.0f * d2) + nk;
      const float q3 = (S3 - 2.0f * d3) + nk;
      const int kg = cb + kl;
      if (q0 < dm0) { dm0 = q0; km0 = kg; }
      if (q1 < dm1) { dm1 = q1; km1 = kg; }
      if (q2 < dm2) { dm2 = q2; km2 = kg; }
      if (q3 < dm3) { dm3 = q3; km3 = kg; }
    }
    __syncthreads();  // done reading buf[cur]; next chunk's loads drained
  }

  // lexicographic (d, k) merge across the 4 k-parities = np first-min
  if (p != 0) {
    dmin_s[(p - 1) * RPB +   0 + r] = dm0;  kmin_s[(p - 1) * RPB +   0 + r] = km0;
    dmin_s[(p - 1) * RPB +  64 + r] = dm1;  kmin_s[(p - 1) * RPB +  64 + r] = km1;
    dmin_s[(p - 1) * RPB + 128 + r] = dm2;  kmin_s[(p - 1) * RPB + 128 + r] = km2;
    dmin_s[(p - 1) * RPB + 192 + r] = dm3;  kmin_s[(p - 1) * RPB + 192 + r] = km3;
  }
  __syncthreads();
  if (p == 0) {
    float dmv[RPT] = {dm0, dm1, dm2, dm3};
    int   kmv[RPT] = {km0, km1, km2, km3};
    double sd = 0.0;
#pragma unroll
    for (int j = 0; j < RPT; ++j) {
      float dmin = dmv[j];
      int   kmin = kmv[j];
#pragma unroll
      for (int q = 0; q < 3; ++q) {
        const float dq = dmin_s[q * RPB + 64 * j + r];
        const int   kq = kmin_s[q * RPB + 64 * j + r];
        if (dq < dmin || (dq == dmin && kq < kmin)) { dmin = dq; kmin = kq; }
      }
      const int n = n0 + 64 * j + r;
      out_idx[n] = (float)kmin;
      atomicAdd(&hist_s[kmin], 1u);

      // epilogue: quantized_st = fl(x + fl(q - x)); loss partial
      const float4* eb = (const float4*)(emb + (size_t)kmin * CDIM);
      float4* o = (float4*)(out0 + (size_t)n * CDIM);
      const float* xj = x + j * CDIM;
      float ssq = 0.f;
#pragma unroll
      for (int c4 = 0; c4 < 16; ++c4) {
        const float4 q4 = eb[c4];
        const float x0 = xj[4*c4+0], x1 = xj[4*c4+1], x2 = xj[4*c4+2], x3 = xj[4*c4+3];
        const float u0 = q4.x - x0, u1 = q4.y - x1, u2 = q4.z - x2, u3 = q4.w - x3;
        ssq = fmaf(u0, u0, fmaf(u1, u1, fmaf(u2, u2, fmaf(u3, u3, ssq))));
        o[c4] = make_float4(x0 + u0, x1 + u1, x2 + u2, x3 + u3);
      }
      sd += (double)ssq;
    }
#pragma unroll
    for (int off = 32; off > 0; off >>= 1) sd += __shfl_down(sd, off, 64);
    if (r == 0) partials[blockIdx.x] = sd;   // deterministic, no FP atomics
  }
  __syncthreads();
  for (int i = t; i < NUM_K; i += 256) {
    const unsigned int v = hist_s[i];
    if (v) atomicAdd(&counts[i], v);
  }
}

__global__ void vq_final(const double* __restrict__ partials,
                         const unsigned int* __restrict__ counts,
                         float* __restrict__ out_loss, float* __restrict__ out_perp)
{
  __shared__ double sh[256];
  const int t = threadIdx.x;
  double acc = 0.0, ent = 0.0;
  for (int i = t; i < NBLK; i += 256) acc += partials[i];
  for (int k = t; k < NUM_K; k += 256) {
    const double pr = (double)counts[k] * (1.0 / 65536.0);
    ent += pr * log(pr + 1e-10);
  }
  sh[t] = acc;
  __syncthreads();
  for (int s = 128; s > 0; s >>= 1) { if (t < s) sh[t] += sh[t + s]; __syncthreads(); }
  const double total = sh[0];
  __syncthreads();
  sh[t] = ent;
  __syncthreads();
  for (int s = 128; s > 0; s >>= 1) { if (t < s) sh[t] += sh[t + s]; __syncthreads(); }
  if (t == 0) {
    // vq_loss = mean((q-x)^2) * (1 + 0.25); means over N*C = 4194304 elements
    out_loss[0] = (float)(1.25 * total / 4194304.0);
    out_perp[0] = (float)exp(-sh[0]);
  }
}

extern "C" void kernel_launch(void* const* d_in, const int* in_sizes, int n_in,
                              void* d_out, int out_size, void* d_ws, size_t ws_size,
                              hipStream_t stream)
{
  const float* xin = (const float*)d_in[0];
  const float* emb = (const float*)d_in[1];
  float* out = (float*)d_out;

  // ws layout: [0,4K) fp32 norms[1024] | [4K,8K) u32 counts[1024] | [8K,16K) f64 partials
  float*        norms    = (float*)d_ws;
  unsigned int* counts   = (unsigned int*)((char*)d_ws + 4096);
  double*       partials = (double*)((char*)d_ws + 8192);

  hipMemsetAsync((char*)d_ws + 4096, 0, 4096, stream);  // zero counts only

  vq_norms<<<dim3(4), dim3(256), 0, stream>>>(emb, norms);

  float* out0     = out;                       // 4194304 elements (BHWC flat)
  float* out_loss = out + 4194304;             // scalar
  float* out_idx  = out + 4194305;             // 65536 elements (as float)
  float* out_perp = out + 4194305 + 65536;     // scalar

  vq_main<<<dim3(NBLK), dim3(256), 0, stream>>>(xin, emb, norms, out0, out_idx,
                                                partials, counts);
  vq_final<<<dim3(1), dim3(256), 0, stream>>>(partials, counts, out_loss, out_perp);
}

// Round 4
// 267.654 us; speedup vs baseline: 1.3401x; 1.1661x over previous
//
#include <hip/hip_runtime.h>
#include <math.h>

#define NUM_K   1024
#define CDIM    64
#define HW      1024          // 32*32
#define NROWS   65536         // 64*1024
#define CHUNK   128           // codes per LDS chunk (32 KB)
#define NCHUNK  (NUM_K / CHUNK)
#define RPT     2             // rows per thread
#define RPB     128           // rows per block = 64 lanes * RPT
#define NBLK    (NROWS / RPB) // 512 blocks -> 2 per CU

typedef float v2f __attribute__((ext_vector_type(2)));

// numpy pairwise_sum order for n=64 contiguous fp32 (8 stride-8 chains,
// ((r0+r1)+(r2+r3))+((r4+r5)+(r6+r7))), squares rounded separately (no FMA).
__device__ __forceinline__ float np_sumsq64(const float* a) {
#pragma clang fp contract(off)
  float r0 = a[0]*a[0], r1 = a[1]*a[1], r2 = a[2]*a[2], r3 = a[3]*a[3];
  float r4 = a[4]*a[4], r5 = a[5]*a[5], r6 = a[6]*a[6], r7 = a[7]*a[7];
#pragma unroll
  for (int i = 8; i < 64; i += 8) {
    r0 += a[i+0]*a[i+0]; r1 += a[i+1]*a[i+1];
    r2 += a[i+2]*a[i+2]; r3 += a[i+3]*a[i+3];
    r4 += a[i+4]*a[i+4]; r5 += a[i+5]*a[i+5];
    r6 += a[i+6]*a[i+6]; r7 += a[i+7]*a[i+7];
  }
  return ((r0+r1)+(r2+r3))+((r4+r5)+(r6+r7));
}

// same reduction order per slot, two rows at once (each slot rounds alone)
__device__ __forceinline__ v2f np_sumsq64_v2(const v2f* a) {
#pragma clang fp contract(off)
  v2f r0 = a[0]*a[0], r1 = a[1]*a[1], r2 = a[2]*a[2], r3 = a[3]*a[3];
  v2f r4 = a[4]*a[4], r5 = a[5]*a[5], r6 = a[6]*a[6], r7 = a[7]*a[7];
#pragma unroll
  for (int i = 8; i < 64; i += 8) {
    r0 += a[i+0]*a[i+0]; r1 += a[i+1]*a[i+1];
    r2 += a[i+2]*a[i+2]; r3 += a[i+3]*a[i+3];
    r4 += a[i+4]*a[i+4]; r5 += a[i+5]*a[i+5];
    r6 += a[i+6]*a[i+6]; r7 += a[i+7]*a[i+7];
  }
  return ((r0+r1)+(r2+r3))+((r4+r5)+(r6+r7));
}

// async global->LDS, 16 B per lane (wave-uniform base + lane*16 pattern)
typedef const __attribute__((address_space(1))) unsigned int* glds_gp;
typedef __attribute__((address_space(3))) unsigned int* glds_lp;
__device__ __forceinline__ void load_lds16(const void* g, void* l) {
  __builtin_amdgcn_global_load_lds((glds_gp)g, (glds_lp)l, 16, 0, 0);
}

__device__ __forceinline__ void stage_chunk(const float* __restrict__ emb,
                                            float* e_dst, int cb, int t) {
  const float4* g = (const float4*)(emb + (size_t)cb * CDIM);
  float4* l = (float4*)e_dst;
#pragma unroll
  for (int i = 0; i < (CHUNK * CDIM / 4) / 256; ++i)   // 8 per thread
    load_lds16(g + t + 256 * i, l + t + 256 * i);
}

__device__ __forceinline__ v2f fma2(v2f a, v2f b, v2f c) {
  return __builtin_elementwise_fma(a, b, c);
}

// 2 blocks/CU, 2 waves/SIMD. x[2][64] = 128 VGPRs/lane; one broadcast e-read
// feeds 2 rows via v_pk_fma_f32 (independent per-slot chains, bit-exact).
__global__ __launch_bounds__(256, 2)
void vq_main(const float* __restrict__ xin, const float* __restrict__ emb,
             float* __restrict__ out0, float* __restrict__ out_idx,
             float* __restrict__ out_loss, float* __restrict__ out_perp,
             double* __restrict__ partials, unsigned int* __restrict__ counts,
             unsigned int* __restrict__ ticket)
{
  __shared__ float e_s[2 * CHUNK * CDIM];   // 64 KB double-buffered
  __shared__ float nk_all[NUM_K];           // 4 KB (all norms resident)
  __shared__ unsigned int hist_s[NUM_K];    // 4 KB
  __shared__ float dmin_s[3 * RPB];         // 1.5 KB
  __shared__ int   kmin_s[3 * RPB];         // 1.5 KB
  __shared__ double shd[256];               // 2 KB (last-block reduce)
  __shared__ int flag_s;

  const int t  = threadIdx.x;
  const int p  = __builtin_amdgcn_readfirstlane(t >> 6);  // k-parity wave
  const int r  = t & 63;
  const int n0 = blockIdx.x * RPB;
  const int b  = n0 >> 10;                  // 128 | 1024 -> same b for block
  const int hw0 = (n0 & (HW - 1)) + r;

  for (int i = t; i < NUM_K; i += 256) hist_s[i] = 0;

  stage_chunk(emb, e_s, 0, t);              // prefetch chunk 0 (async)

  // fused norms: every block computes all 1024 ||e_k||^2 (np order, L2-hot)
#pragma unroll
  for (int i = 0; i < 4; ++i) {
    const int k = t + 256 * i;
    nk_all[k] = np_sumsq64(emb + (size_t)k * CDIM);
  }

  // gather 2 rows per lane from BHWC (coalesced across lanes per c)
  const float* xb = xin + (size_t)b * (CDIM * HW);
  v2f xp[CDIM];
#pragma unroll
  for (int c = 0; c < CDIM; ++c) {
    const float f0 = xb[(c << 10) + hw0];
    const float f1 = xb[(c << 10) + hw0 + 64];
    xp[c] = (v2f){f0, f1};
  }
  const v2f S = np_sumsq64_v2(xp);   // per-slot bit-match of np.sum(x*x)

  v2f   dmv = {INFINITY, INFINITY};
  int   km0 = 0, km1 = 0;
  float dm0 = INFINITY, dm1 = INFINITY;

  __syncthreads();   // chunk 0 staged; nk_all ready

  for (int ci = 0; ci < NCHUNK; ++ci) {
    if (ci + 1 < NCHUNK)
      stage_chunk(emb, e_s + ((ci + 1) & 1) * (CHUNK * CDIM), (ci + 1) << 7, t);

    const float* es = e_s + (ci & 1) * (CHUNK * CDIM);
    const int cb = ci << 7;

    for (int g = 0; g < 16; ++g) {          // 2 k's in flight: 8g+p, 8g+4+p
      const int kl0 = 8 * g + p;
      const int kl1 = kl0 + 4;
      const float4* e0p = (const float4*)(es + kl0 * CDIM);
      const float4* e1p = (const float4*)(es + kl1 * CDIM);
      const float nk0 = nk_all[cb + kl0];
      const float nk1 = nk_all[cb + kl1];
      v2f dp0 = {0.f, 0.f}, dp1 = {0.f, 0.f};
#pragma unroll
      for (int c4 = 0; c4 < 16; ++c4) {
        const float4 a0 = e0p[c4];          // broadcast b128 serves 2 rows
        const float4 a1 = e1p[c4];
        const v2f x0 = xp[4*c4+0], x1 = xp[4*c4+1];
        const v2f x2 = xp[4*c4+2], x3 = xp[4*c4+3];
        dp0 = fma2(x0, (v2f){a0.x, a0.x}, dp0);
        dp1 = fma2(x0, (v2f){a1.x, a1.x}, dp1);
        dp0 = fma2(x1, (v2f){a0.y, a0.y}, dp0);
        dp1 = fma2(x1, (v2f){a1.y, a1.y}, dp1);
        dp0 = fma2(x2, (v2f){a0.z, a0.z}, dp0);
        dp1 = fma2(x2, (v2f){a1.z, a1.z}, dp1);
        dp0 = fma2(x3, (v2f){a0.w, a0.w}, dp0);
        dp1 = fma2(x3, (v2f){a1.w, a1.w}, dp1);
      }
      // q = fl(fl(S-2d)+nk); 2d exact so fma contraction is bit-identical
      const float q00 = (S.x - 2.0f * dp0.x) + nk0;
      const float q01 = (S.y - 2.0f * dp0.y) + nk0;
      const float q10 = (S.x - 2.0f * dp1.x) + nk1;
      const float q11 = (S.y - 2.0f * dp1.y) + nk1;
      const int kg0 = cb + kl0, kg1 = cb + kl1;
      if (q00 < dm0) { dm0 = q00; km0 = kg0; }
      if (q01 < dm1) { dm1 = q01; km1 = kg0; }
      if (q10 < dm0) { dm0 = q10; km0 = kg1; }
      if (q11 < dm1) { dm1 = q11; km1 = kg1; }
    }
    __syncthreads();
  }
  (void)dmv;

  // lexicographic (d,k) merge across the 4 parities = np first-min semantics
  if (p != 0) {
    dmin_s[(p - 1) * RPB +  0 + r] = dm0;  kmin_s[(p - 1) * RPB +  0 + r] = km0;
    dmin_s[(p - 1) * RPB + 64 + r] = dm1;  kmin_s[(p - 1) * RPB + 64 + r] = km1;
  }
  __syncthreads();
  if (p == 0) {
    float dmv2[RPT] = {dm0, dm1};
    int   kmv2[RPT] = {km0, km1};
    double sd = 0.0;
#pragma unroll
    for (int j = 0; j < RPT; ++j) {
      float dmin = dmv2[j];
      int   kmin = kmv2[j];
#pragma unroll
      for (int q = 0; q < 3; ++q) {
        const float dq = dmin_s[q * RPB + 64 * j + r];
        const int   kq = kmin_s[q * RPB + 64 * j + r];
        if (dq < dmin || (dq == dmin && kq < kmin)) { dmin = dq; kmin = kq; }
      }
      const int n = n0 + 64 * j + r;
      out_idx[n] = (float)kmin;
      atomicAdd(&hist_s[kmin], 1u);

      const float4* eb = (const float4*)(emb + (size_t)kmin * CDIM);
      float4* o = (float4*)(out0 + (size_t)n * CDIM);
      float ssq = 0.f;
#pragma unroll
      for (int c4 = 0; c4 < 16; ++c4) {
        const float4 q4 = eb[c4];
        const float x0 = xp[4*c4+0][j], x1 = xp[4*c4+1][j];
        const float x2 = xp[4*c4+2][j], x3 = xp[4*c4+3][j];
        const float u0 = q4.x - x0, u1 = q4.y - x1, u2 = q4.z - x2, u3 = q4.w - x3;
        ssq = fmaf(u0, u0, fmaf(u1, u1, fmaf(u2, u2, fmaf(u3, u3, ssq))));
        o[c4] = make_float4(x0 + u0, x1 + u1, x2 + u2, x3 + u3);
      }
      sd += (double)ssq;
    }
#pragma unroll
    for (int off = 32; off > 0; off >>= 1) sd += __shfl_down(sd, off, 64);
    if (r == 0) partials[blockIdx.x] = sd;
  }
  __syncthreads();
  for (int i = t; i < NUM_K; i += 256) {
    const unsigned int v = hist_s[i];
    if (v) atomicAdd(&counts[i], v);
  }

  // ---- last-block finalization (replaces vq_final launch) ----
  __threadfence();          // release this thread's stores/atomics device-wide
  __syncthreads();
  if (t == 0) {
    const unsigned int old = atomicAdd(ticket, 1u);
    flag_s = (old == NBLK - 1);
  }
  __syncthreads();
  if (!flag_s) return;
  __threadfence();          // acquire

  volatile const double* vp = partials;
  volatile const unsigned int* vc = counts;
  double acc = 0.0, ent = 0.0;
  for (int i = t; i < NBLK; i += 256) acc += vp[i];
  for (int k = t; k < NUM_K; k += 256) {
    const double pr = (double)vc[k] * (1.0 / 65536.0);
    ent += pr * log(pr + 1e-10);
  }
  shd[t] = acc;
  __syncthreads();
  for (int s = 128; s > 0; s >>= 1) { if (t < s) shd[t] += shd[t + s]; __syncthreads(); }
  const double total = shd[0];
  __syncthreads();
  shd[t] = ent;
  __syncthreads();
  for (int s = 128; s > 0; s >>= 1) { if (t < s) shd[t] += shd[t + s]; __syncthreads(); }
  if (t == 0) {
    out_loss[0] = (float)(1.25 * total / 4194304.0);
    out_perp[0] = (float)exp(-shd[0]);
  }
}

extern "C" void kernel_launch(void* const* d_in, const int* in_sizes, int n_in,
                              void* d_out, int out_size, void* d_ws, size_t ws_size,
                              hipStream_t stream)
{
  const float* xin = (const float*)d_in[0];
  const float* emb = (const float*)d_in[1];
  float* out = (float*)d_out;

  // ws: [0,4K) u32 counts | [4K,4K+256) ticket | [8K,12K) f64 partials[512]
  unsigned int* counts   = (unsigned int*)d_ws;
  unsigned int* ticket   = (unsigned int*)((char*)d_ws + 4096);
  double*       partials = (double*)((char*)d_ws + 8192);

  hipMemsetAsync(d_ws, 0, 4096 + 256, stream);   // zero counts + ticket

  float* out0     = out;                       // 4194304 elements (BHWC flat)
  float* out_loss = out + 4194304;             // scalar
  float* out_idx  = out + 4194305;             // 65536 elements (as float)
  float* out_perp = out + 4194305 + 65536;     // scalar

  vq_main<<<dim3(NBLK), dim3(256), 0, stream>>>(xin, emb, out0, out_idx,
                                                out_loss, out_perp,
                                                partials, counts, ticket);
}